// Round 18
// baseline (286.791 us; speedup 1.0000x reference)
//
#include <hip/hip_runtime.h>
#include <hip/hip_bf16.h>

#define QN 150
#define CN 512
#define HWN 441
#define WAYN 5
#define SHOTN 5
#define NSAMP 2205           // SHOT*HW
#define MROWS (QN * HWN)     // 66150 packed rows
#define MT128 517            // ceil(66150/128)
#define MPAD2 66304
#define KP 2208              // cov K padded (32*69)
#define KPB (KP * 2)         // row bytes of x2c

typedef unsigned short u16;
typedef unsigned int u32;
typedef __attribute__((ext_vector_type(8))) short short8;
typedef __attribute__((ext_vector_type(4))) float f32x4;

__device__ __forceinline__ u16 f2b(float f) {
    return __builtin_bit_cast(u16, __float2bfloat16(f));
}
__device__ __forceinline__ float b2f(u16 h) {
    u32 u = ((u32)h) << 16;
    return __builtin_bit_cast(float, u);
}

__device__ __forceinline__ void gload16(const void* g, void* l) {
    __builtin_amdgcn_global_load_lds(
        (const __attribute__((address_space(1))) unsigned int*)g,
        (__attribute__((address_space(3))) unsigned int*)l, 16, 0, 0);
}

// pair index p in [0,10) -> (lo, hi) with lo <= hi over 4 blocks of 128
__device__ __forceinline__ void pair_decode(int p, int& lo, int& hi) {
    hi = (p >= 6) ? 3 : (p >= 3 ? 2 : (p >= 1 ? 1 : 0));
    int tri = (hi == 3) ? 6 : (hi == 2 ? 3 : (hi == 1 ? 1 : 0));
    lo = p - tri;
}

// ---------------- fused: per-(way,channel) mean + center x2 -> bf16 x2c[w][c][k] ----------------
__global__ void wx2c_kernel(const float* __restrict__ x2, u16* __restrict__ x2c) {
    int b = blockIdx.x;             // w*512 + c
    int w = b >> 9, c = b & 511;
    int lane = threadIdx.x;         // 64
    float s = 0.f;
    #pragma unroll
    for (int sh = 0; sh < SHOTN; ++sh) {
        const float* p = x2 + ((size_t)((w * SHOTN + sh) * CN + c)) * HWN;
        for (int i = lane; i < HWN; i += 64) s += p[i];
    }
    #pragma unroll
    for (int off = 32; off > 0; off >>= 1) s += __shfl_down(s, off);
    float m = __shfl(s, 0) * (1.0f / NSAMP);

    u16* dst = x2c + ((size_t)(w * CN + c)) * KP;
    #pragma unroll
    for (int sh = 0; sh < SHOTN; ++sh) {
        const float* p = x2 + ((size_t)((w * SHOTN + sh) * CN + c)) * HWN;
        for (int i = lane; i < HWN; i += 64) dst[sh * HWN + i] = f2b(p[i] - m);
    }
    if (lane < (KP - NSAMP)) dst[NSAMP + lane] = 0;
}

// ---------------- cov MFMA split-K(6), lower-triangle 128-blocks only ----------------
// grid (10, 1, 30): z = w*6 + ksp; ksp<3: 12 chunks, else 11 (offsets 0/12/24/36/47/58; total 69)
__global__ __launch_bounds__(256, 2) void covmfma_kernel(const u16* __restrict__ x2c,
                                                         float* __restrict__ covf) {
    __shared__ __align__(16) u16 As[2][128 * 32];
    __shared__ __align__(16) u16 Bs[2][128 * 32];
    int z  = blockIdx.z;
    int w  = z / 6, ksp = z - w * 6;
    int kchunks = (ksp < 3) ? 12 : 11;
    int kcoff   = (ksp < 3) ? ksp * 12 : 36 + (ksp - 3) * 11;   // chunk offset
    int dblk, cblk;
    pair_decode(blockIdx.x, dblk, cblk);    // cblk >= dblk
    int c0 = cblk * 128;
    int d0 = dblk * 128;
    int t = threadIdx.x;
    int lane = t & 63, wid = t >> 6;
    int wr = wid >> 1, wc = wid & 1;
    int rl = lane & 15, g4 = lane >> 4;
    int swz = ((rl >> 1) & 3) << 4;
    int s0 = wid * 2048 + lane * 16;

    const char* gX = (const char*)(x2c + (size_t)w * CN * KP) + kcoff * 64;

    f32x4 acc[4][4];
    #pragma unroll
    for (int mi = 0; mi < 4; ++mi)
        #pragma unroll
        for (int ni = 0; ni < 4; ++ni)
            acc[mi][ni] = (f32x4){0.f, 0.f, 0.f, 0.f};

    int buf = 0;
    #pragma unroll
    for (int j = 0; j < 2; ++j) {
        int s = s0 + j * 1024;
        int row = s >> 6, kbs = (s & 63) ^ (((row >> 1) & 3) << 4);
        gload16(gX + (size_t)(c0 + row) * KPB + kbs, (char*)&As[0][0] + wid * 2048 + j * 1024);
        gload16(gX + (size_t)(d0 + row) * KPB + kbs, (char*)&Bs[0][0] + wid * 2048 + j * 1024);
    }
    __syncthreads();

    for (int ks = 0; ks < kchunks; ++ks) {
        if (ks < kchunks - 1) {
            int koff = (ks + 1) * 64;
            #pragma unroll
            for (int j = 0; j < 2; ++j) {
                int s = s0 + j * 1024;
                int row = s >> 6, kbs = (s & 63) ^ (((row >> 1) & 3) << 4);
                gload16(gX + (size_t)(c0 + row) * KPB + koff + kbs,
                        (char*)&As[buf ^ 1][0] + wid * 2048 + j * 1024);
                gload16(gX + (size_t)(d0 + row) * KPB + koff + kbs,
                        (char*)&Bs[buf ^ 1][0] + wid * 2048 + j * 1024);
            }
        }
        const char* Ab = (const char*)&As[buf][0];
        const char* Bb = (const char*)&Bs[buf][0];
        int kread = (g4 * 16) ^ swz;
        short8 a[4], b[4];
        #pragma unroll
        for (int mi = 0; mi < 4; ++mi)
            a[mi] = *(const short8*)(Ab + (wr * 64 + mi * 16 + rl) * 64 + kread);
        #pragma unroll
        for (int ni = 0; ni < 4; ++ni)
            b[ni] = *(const short8*)(Bb + (wc * 64 + ni * 16 + rl) * 64 + kread);
        #pragma unroll
        for (int mi = 0; mi < 4; ++mi)
            #pragma unroll
            for (int ni = 0; ni < 4; ++ni)
                acc[mi][ni] = __builtin_amdgcn_mfma_f32_16x16x32_bf16(
                    a[mi], b[ni], acc[mi][ni], 0, 0, 0);
        __syncthreads();
        buf ^= 1;
    }

    const float inv = 1.0f / (NSAMP - 1);
    #pragma unroll
    for (int mi = 0; mi < 4; ++mi)
        #pragma unroll
        for (int r = 0; r < 4; ++r) {
            int c = c0 + wr * 64 + mi * 16 + g4 * 4 + r;
            #pragma unroll
            for (int ni = 0; ni < 4; ++ni) {
                int d = d0 + wc * 64 + ni * 16 + rl;
                atomicAdd(&covf[((size_t)w * CN + c) * CN + d], acc[mi][ni][r] * inv);
            }
        }
}

// ---------------- covf (lower-tri blocks) -> covb bf16, symmetrized; cross block pre-scaled x2 ----------------
__global__ void cov2b_kernel(const float* __restrict__ covf, u16* __restrict__ covb) {
    int i = blockIdx.x * 256 + threadIdx.x;        // w*CN*CN + c*CN + d   (c = B row = output-d, d = k)
    int w = i >> 18;
    int cd = i & ((1 << 18) - 1);
    int c = cd >> 9, d = cd & 511;
    int cb = c >> 7, db = d >> 7;
    size_t src;
    if (cb >= db) src = ((size_t)w << 18) + ((size_t)c << 9) + d;
    else          src = ((size_t)w << 18) + ((size_t)d << 9) + c;   // mirror from lower block
    float v = covf[src];
    if (c >= 256 && d < 256) v *= 2.f;     // fold symmetry weight into cross block
    covb[i] = f2b(v);
}

// ---------------- transpose+center x1 -> Abf[(q*441+i)][c] bf16 (packed rows) ----------------
__global__ __launch_bounds__(256) void qtrans_kernel(const float* __restrict__ x1,
                                                     u16* __restrict__ Abf) {
    __shared__ u16 S[512][72];
    __shared__ float qm[64];
    int c0 = blockIdx.x * 64;
    int q  = blockIdx.y;
    int t = threadIdx.x;
    int lane = t & 63, cq = t >> 6;

    for (int cc = cq; cc < 64; cc += 4) {
        int c = c0 + cc;
        const float* p = x1 + ((size_t)q * CN + c) * HWN;
        float s = 0.f;
        for (int ic = 0; ic < 8; ++ic) {
            int i = ic * 64 + lane;
            float v = (i < HWN) ? p[i] : 0.f;
            s += v;
            S[i][cc] = f2b(v);
        }
        #pragma unroll
        for (int off = 32; off > 0; off >>= 1) s += __shfl_down(s, off);
        if (lane == 0) qm[cc] = s * (1.0f / HWN);
    }
    __syncthreads();

    int coct = t & 7;
    for (int p = 0; p < 16; ++p) {
        int il = p * 32 + (t >> 3);
        if (il >= HWN) continue;
        short8 v = *(const short8*)(&S[il][coct * 8]);
        short8 o;
        #pragma unroll
        for (int j = 0; j < 8; ++j) {
            float f = b2f((u16)v[j]) - qm[coct * 8 + j];
            o[j] = (short)f2b(f);
        }
        *(short8*)(Abf + ((size_t)(q * HWN + il)) * CN + c0 + coct * 8) = o;
    }
}

// ---------------- init: zero simws + covf + Abf pad rows ----------------
__global__ void init2_kernel(float* __restrict__ simws, float* __restrict__ covf,
                             u32* __restrict__ AbfPad32) {
    int tid = blockIdx.x * blockDim.x + threadIdx.x;
    int stride = gridDim.x * blockDim.x;
    int nsim = WAYN * MPAD2;
    for (int i = tid; i < nsim; i += stride) simws[i] = 0.f;
    int ncov = WAYN * CN * CN;
    for (int i = tid; i < ncov; i += stride) covf[i] = 0.f;
    int npadw = (MPAD2 - MROWS) * CN / 2;
    for (int i = tid; i < npadw; i += stride) AbfPad32[i] = 0;
}

// ---------------- main: 128x128 tile, 4 waves, 4 blocks/CU, variable-K d-slice blocks ----------------
// One block per (m-tile, w, d-slice). With cross block pre-scaled 2x in covb:
//   d-slice 0: d=[0,128)   K=[0,256)  -> 8 chunks
//   d-slice 1: d=[128,256) K=[0,256)  -> 8 chunks
//   d-slice 2: d=[256,384) K=[0,512)  -> 16 chunks
//   d-slice 3: d=[384,512) K=[0,512)  -> 16 chunks
// 48 chunks per (m,w) (0.75x FLOPs) over 4 blocks -> 10400 blocks. (256,4): VGPR 60+64=124<=128,
// LDS 33.5KBx4=134<=160KB -> 16 waves/CU for max cross-block overlap (r14 mechanism).
__global__ __launch_bounds__(256, 4) void gemm128v_kernel(const u16* __restrict__ Abf,
                                                          const u16* __restrict__ covb,
                                                          float* __restrict__ simws) {
    __shared__ __align__(16) u16 As[2][128 * 32];
    __shared__ __align__(16) u16 Bs[2][128 * 32];
    __shared__ float simpart[128 * 3];

    int x = blockIdx.x & 7;
    int l = blockIdx.x >> 3;
    int g = l / 20;
    int m = x * 65 + g;
    if (m >= MT128) return;
    int inner = l - g * 20;
    int w  = inner % 5;
    int dsl = inner / 5;                 // 0..3
    int n0 = dsl * 128;
    int NCH = (dsl < 2) ? 8 : 16;        // K = 256 or 512
    int r0 = m * 128;

    int t = threadIdx.x;
    int lane = t & 63, wid = t >> 6;
    int wr = wid >> 1, wc = wid & 1;        // 2M x 2N waves, wave tile 64x64
    int rl = lane & 15, g4 = lane >> 4;
    int swz = ((rl >> 1) & 3) << 4;
    int kread = (g4 * 16) ^ swz;

    const char* gA = (const char*)(Abf + (size_t)r0 * CN);               // row stride 1024 B
    const char* gB = (const char*)(covb + ((size_t)w * CN + n0) * CN);   // row stride 1024 B

    f32x4 acc[4][4];
    #pragma unroll
    for (int mi = 0; mi < 4; ++mi)
        #pragma unroll
        for (int ni = 0; ni < 4; ++ni)
            acc[mi][ni] = (f32x4){0.f, 0.f, 0.f, 0.f};

    // stage chunk kc into slot kc&1: 2 A + 2 B gload16 per thread (8 KB each op)
    auto stage_chunk = [&](int kc) {
        int slot = kc & 1;
        int kbyte = kc * 64;
        #pragma unroll
        for (int j = 0; j < 2; ++j) {
            int off = j * 4096 + t * 16;
            int row = off >> 6;
            int kbs = (off & 63) ^ (((row >> 1) & 3) << 4);
            gload16(gA + (size_t)row * 1024 + kbyte + kbs, (char*)&As[slot][0] + off);
            gload16(gB + (size_t)row * 1024 + kbyte + kbs, (char*)&Bs[slot][0] + off);
        }
    };

    // merged chunk body (r14-proven): 8 ds_reads (b/a interleaved) then 16 MFMA
    auto do_chunk = [&](int c) {
        const char* Ab = (const char*)&As[c & 1][0];
        const char* Bb = (const char*)&Bs[c & 1][0];
        short8 a[4], b[4];
        #pragma unroll
        for (int ni = 0; ni < 4; ++ni) {
            b[ni] = *(const short8*)(Bb + (wc * 64 + ni * 16 + rl) * 64 + kread);
            a[ni] = *(const short8*)(Ab + (wr * 64 + ni * 16 + rl) * 64 + kread);
        }
        __builtin_amdgcn_s_setprio(1);
        #pragma unroll
        for (int mi = 0; mi < 4; ++mi)
            #pragma unroll
            for (int ni = 0; ni < 4; ++ni)
                acc[mi][ni] = __builtin_amdgcn_mfma_f32_16x16x32_bf16(
                    a[mi], b[ni], acc[mi][ni], 0, 0, 0);
        __builtin_amdgcn_s_setprio(0);
        // reads retired before MFMAs issued -> next top barrier closes this slot
    };

    stage_chunk(0);

    #pragma unroll 1
    for (int c = 0; c < NCH; ++c) {
        asm volatile("s_waitcnt vmcnt(0)" ::: "memory");   // chunk-c loads landed
        __builtin_amdgcn_s_barrier();
        asm volatile("" ::: "memory");
        if (c + 1 < NCH) stage_chunk(c + 1);               // depth-1 prefetch into other slot
        do_chunk(c);
    }

    // epilogue: partial sim over this block's 128 d-columns
    __syncthreads();
    #pragma unroll
    for (int mi = 0; mi < 4; ++mi) {
        #pragma unroll
        for (int r = 0; r < 4; ++r) {
            int Rl = wr * 64 + mi * 16 + g4 * 4 + r;
            size_t Rg = (size_t)r0 + Rl;
            float s = 0.f;
            #pragma unroll
            for (int ni = 0; ni < 4; ++ni) {
                int d = n0 + wc * 64 + ni * 16 + rl;
                s += acc[mi][ni][r] * b2f(Abf[Rg * CN + d]);
            }
            s += __shfl_xor(s, 1);
            s += __shfl_xor(s, 2);
            s += __shfl_xor(s, 4);
            s += __shfl_xor(s, 8);
            if (rl == 0) simpart[Rl * 3 + wc] = s;
        }
    }
    __syncthreads();
    if (t < 128) {
        float v = simpart[t * 3 + 0] + simpart[t * 3 + 1];
        atomicAdd(&simws[(size_t)w * MPAD2 + r0 + t], v);
    }
}

// ---------------- finish: act + conv dot + bias -> scores ----------------
__global__ void finish_kernel(const float* __restrict__ simws,
                              const float* __restrict__ conv_w,
                              const float* __restrict__ conv_b,
                              float* __restrict__ scores) {
    int q = blockIdx.x, w = blockIdx.y;
    int t = threadIdx.x;    // 128
    const float* sp = simws + (size_t)w * MPAD2 + q * HWN;
    float s = 0.f;
    for (int i = t; i < HWN; i += 128) {
        float v = sp[i];
        float a = (v >= 0.f) ? v : 0.2f * v;
        s += a * conv_w[i];
    }
    __shared__ float red[2];
    #pragma unroll
    for (int off = 32; off > 0; off >>= 1) s += __shfl_down(s, off);
    if ((t & 63) == 0) red[t >> 6] = s;
    __syncthreads();
    if (t == 0) scores[q * WAYN + w] = red[0] + red[1] + conv_b[0];
}

extern "C" void kernel_launch(void* const* d_in, const int* in_sizes, int n_in,
                              void* d_out, int out_size, void* d_ws, size_t ws_size,
                              hipStream_t stream) {
    const float* x1     = (const float*)d_in[0];
    const float* x2     = (const float*)d_in[1];
    const float* conv_w = (const float*)d_in[2];
    const float* conv_b = (const float*)d_in[3];
    float* scores = (float*)d_out;

    char* ws = (char*)d_ws;
    u16* covb    = (u16*)ws;                               // 2,621,440 B
    float* simws = (float*)(ws + 2631680);                 // 1,326,080 B
    float* covf  = (float*)(ws + 3957760);                 // 5,242,880 B
    // x2c aliases head of Abf (covmfma reads x2c before qtrans writes Abf)
    u16* x2c     = (u16*)(ws + 9200640);                   // 11,304,960 B
    u16* Abf     = (u16*)(ws + 9200640);                   // 66304*512*2 = 67,895,296 B

    wx2c_kernel<<<WAYN * CN, 64, 0, stream>>>(x2, x2c);
    init2_kernel<<<256, 256, 0, stream>>>(simws, covf, (u32*)(Abf + (size_t)MROWS * CN));
    covmfma_kernel<<<dim3(10, 1, WAYN * 6), 256, 0, stream>>>(x2c, covf);
    cov2b_kernel<<<WAYN * CN * CN / 256, 256, 0, stream>>>(covf, covb);
    qtrans_kernel<<<dim3(8, QN), 256, 0, stream>>>(x1, Abf);
    gemm128v_kernel<<<8 * 65 * 20, 256, 0, stream>>>(Abf, covb, simws);
    finish_kernel<<<dim3(QN, WAYN), 128, 0, stream>>>(simws, conv_w, conv_b, scores);
}

// Round 19
// 271.121 us; speedup vs baseline: 1.0578x; 1.0578x over previous
//
#include <hip/hip_runtime.h>
#include <hip/hip_bf16.h>

#define QN 150
#define CN 512
#define HWN 441
#define WAYN 5
#define SHOTN 5
#define NSAMP 2205           // SHOT*HW
#define MROWS (QN * HWN)     // 66150 packed rows
#define MT128 517            // ceil(66150/128)
#define MPAD2 66304
#define KP 2208              // cov K padded (32*69)
#define KPB (KP * 2)         // row bytes of x2c

typedef unsigned short u16;
typedef unsigned int u32;
typedef __attribute__((ext_vector_type(8))) short short8;
typedef __attribute__((ext_vector_type(4))) float f32x4;

__device__ __forceinline__ u16 f2b(float f) {
    return __builtin_bit_cast(u16, __float2bfloat16(f));
}
__device__ __forceinline__ float b2f(u16 h) {
    u32 u = ((u32)h) << 16;
    return __builtin_bit_cast(float, u);
}

__device__ __forceinline__ void gload16(const void* g, void* l) {
    __builtin_amdgcn_global_load_lds(
        (const __attribute__((address_space(1))) unsigned int*)g,
        (__attribute__((address_space(3))) unsigned int*)l, 16, 0, 0);
}

// pair index p in [0,10) -> (lo, hi) with lo <= hi over 4 blocks of 128
__device__ __forceinline__ void pair_decode(int p, int& lo, int& hi) {
    hi = (p >= 6) ? 3 : (p >= 3 ? 2 : (p >= 1 ? 1 : 0));
    int tri = (hi == 3) ? 6 : (hi == 2 ? 3 : (hi == 1 ? 1 : 0));
    lo = p - tri;
}

// ---------------- prep1 (fused): wx2c (blocks 0..639, 4 (w,c)/block) + zero-init (blocks 640..895) ----------------
__global__ __launch_bounds__(256) void prep1_kernel(const float* __restrict__ x2,
                                                    u16* __restrict__ x2c,
                                                    float* __restrict__ simws,
                                                    float* __restrict__ covf,
                                                    u32* __restrict__ AbfPad32) {
    int t = threadIdx.x;
    if (blockIdx.x < 640) {
        // wx2c role: per-wave (w,c) mean + center -> bf16 x2c[w][c][k]
        int lane = t & 63, sub = t >> 6;
        int b = blockIdx.x * 4 + sub;   // 0..2559 = w*512 + c
        int w = b >> 9, c = b & 511;
        float s = 0.f;
        #pragma unroll
        for (int sh = 0; sh < SHOTN; ++sh) {
            const float* p = x2 + ((size_t)((w * SHOTN + sh) * CN + c)) * HWN;
            for (int i = lane; i < HWN; i += 64) s += p[i];
        }
        #pragma unroll
        for (int off = 32; off > 0; off >>= 1) s += __shfl_down(s, off);
        float m = __shfl(s, 0) * (1.0f / NSAMP);

        u16* dst = x2c + ((size_t)(w * CN + c)) * KP;
        #pragma unroll
        for (int sh = 0; sh < SHOTN; ++sh) {
            const float* p = x2 + ((size_t)((w * SHOTN + sh) * CN + c)) * HWN;
            for (int i = lane; i < HWN; i += 64) dst[sh * HWN + i] = f2b(p[i] - m);
        }
        if (lane < (KP - NSAMP)) dst[NSAMP + lane] = 0;
    } else {
        // init role: zero simws + covf + Abf pad rows
        int tid = (blockIdx.x - 640) * 256 + t;
        int stride = 256 * 256;
        int nsim = WAYN * MPAD2;
        for (int i = tid; i < nsim; i += stride) simws[i] = 0.f;
        int ncov = WAYN * CN * CN;
        for (int i = tid; i < ncov; i += stride) covf[i] = 0.f;
        int npadw = (MPAD2 - MROWS) * CN / 2;
        for (int i = tid; i < npadw; i += stride) AbfPad32[i] = 0;
    }
}

// ---------------- prep2 (fused, heterogeneous): covmfma (blocks 0..299) || qtrans (blocks 300..1499) ----------------
// covmfma: split-K(6), lower-triangle 128-blocks; pair = bid%10, z = bid/10 (w*6+ksp).
// qtrans:  qb = bid-300: c0 = (qb&7)*64, q = qb>>3.
// Shared: union — cov role 32 KB (As/Bs dbuf), qtrans role 74 KB (S[512][72]+qm) -> 2 blocks/CU both.
__global__ __launch_bounds__(256, 2) void prep2_kernel(const u16* __restrict__ x2c,
                                                       float* __restrict__ covf,
                                                       const float* __restrict__ x1,
                                                       u16* __restrict__ Abf) {
    __shared__ __align__(16) char smem[73984];
    int t = threadIdx.x;

    if (blockIdx.x < 300) {
        // ======== covmfma role ========
        u16* As0 = (u16*)smem;                    // [2][128*32]
        u16* Bs0 = (u16*)(smem + 16384);
        int bid = blockIdx.x;
        int z = bid / 10;
        int pr = bid - z * 10;
        int w  = z / 6, ksp = z - w * 6;
        int kchunks = (ksp < 3) ? 12 : 11;
        int kcoff   = (ksp < 3) ? ksp * 12 : 36 + (ksp - 3) * 11;
        int dblk, cblk;
        pair_decode(pr, dblk, cblk);    // cblk >= dblk
        int c0 = cblk * 128;
        int d0 = dblk * 128;
        int lane = t & 63, wid = t >> 6;
        int wr = wid >> 1, wc = wid & 1;
        int rl = lane & 15, g4 = lane >> 4;
        int swz = ((rl >> 1) & 3) << 4;
        int s0 = wid * 2048 + lane * 16;

        const char* gX = (const char*)(x2c + (size_t)w * CN * KP) + kcoff * 64;

        f32x4 acc[4][4];
        #pragma unroll
        for (int mi = 0; mi < 4; ++mi)
            #pragma unroll
            for (int ni = 0; ni < 4; ++ni)
                acc[mi][ni] = (f32x4){0.f, 0.f, 0.f, 0.f};

        int buf = 0;
        #pragma unroll
        for (int j = 0; j < 2; ++j) {
            int s = s0 + j * 1024;
            int row = s >> 6, kbs = (s & 63) ^ (((row >> 1) & 3) << 4);
            gload16(gX + (size_t)(c0 + row) * KPB + kbs, (char*)As0 + wid * 2048 + j * 1024);
            gload16(gX + (size_t)(d0 + row) * KPB + kbs, (char*)Bs0 + wid * 2048 + j * 1024);
        }
        __syncthreads();

        for (int ks = 0; ks < kchunks; ++ks) {
            if (ks < kchunks - 1) {
                int koff = (ks + 1) * 64;
                #pragma unroll
                for (int j = 0; j < 2; ++j) {
                    int s = s0 + j * 1024;
                    int row = s >> 6, kbs = (s & 63) ^ (((row >> 1) & 3) << 4);
                    gload16(gX + (size_t)(c0 + row) * KPB + koff + kbs,
                            (char*)As0 + (buf ^ 1) * 8192 + wid * 2048 + j * 1024);
                    gload16(gX + (size_t)(d0 + row) * KPB + koff + kbs,
                            (char*)Bs0 + (buf ^ 1) * 8192 + wid * 2048 + j * 1024);
                }
            }
            const char* Ab = (const char*)As0 + buf * 8192;
            const char* Bb = (const char*)Bs0 + buf * 8192;
            int kread = (g4 * 16) ^ swz;
            short8 a[4], b[4];
            #pragma unroll
            for (int mi = 0; mi < 4; ++mi)
                a[mi] = *(const short8*)(Ab + (wr * 64 + mi * 16 + rl) * 64 + kread);
            #pragma unroll
            for (int ni = 0; ni < 4; ++ni)
                b[ni] = *(const short8*)(Bb + (wc * 64 + ni * 16 + rl) * 64 + kread);
            #pragma unroll
            for (int mi = 0; mi < 4; ++mi)
                #pragma unroll
                for (int ni = 0; ni < 4; ++ni)
                    acc[mi][ni] = __builtin_amdgcn_mfma_f32_16x16x32_bf16(
                        a[mi], b[ni], acc[mi][ni], 0, 0, 0);
            __syncthreads();
            buf ^= 1;
        }

        const float inv = 1.0f / (NSAMP - 1);
        #pragma unroll
        for (int mi = 0; mi < 4; ++mi)
            #pragma unroll
            for (int r = 0; r < 4; ++r) {
                int c = c0 + wr * 64 + mi * 16 + g4 * 4 + r;
                #pragma unroll
                for (int ni = 0; ni < 4; ++ni) {
                    int d = d0 + wc * 64 + ni * 16 + rl;
                    atomicAdd(&covf[((size_t)w * CN + c) * CN + d], acc[mi][ni][r] * inv);
                }
            }
    } else {
        // ======== qtrans role ========
        u16 (*S)[72] = (u16(*)[72])smem;            // [512][72]
        float* qm = (float*)(smem + 73728);         // [64]
        int qb = blockIdx.x - 300;
        int c0 = (qb & 7) * 64;
        int q  = qb >> 3;
        int lane = t & 63, cq = t >> 6;

        for (int cc = cq; cc < 64; cc += 4) {
            int c = c0 + cc;
            const float* p = x1 + ((size_t)q * CN + c) * HWN;
            float s = 0.f;
            for (int ic = 0; ic < 8; ++ic) {
                int i = ic * 64 + lane;
                float v = (i < HWN) ? p[i] : 0.f;
                s += v;
                S[i][cc] = f2b(v);
            }
            #pragma unroll
            for (int off = 32; off > 0; off >>= 1) s += __shfl_down(s, off);
            if (lane == 0) qm[cc] = s * (1.0f / HWN);
        }
        __syncthreads();

        int coct = t & 7;
        for (int p = 0; p < 16; ++p) {
            int il = p * 32 + (t >> 3);
            if (il >= HWN) continue;
            short8 v = *(const short8*)(&S[il][coct * 8]);
            short8 o;
            #pragma unroll
            for (int j = 0; j < 8; ++j) {
                float f = b2f((u16)v[j]) - qm[coct * 8 + j];
                o[j] = (short)f2b(f);
            }
            *(short8*)(Abf + ((size_t)(q * HWN + il)) * CN + c0 + coct * 8) = o;
        }
    }
}

// ---------------- covf (lower-tri blocks) -> covb bf16, symmetrized; cross block pre-scaled x2 ----------------
__global__ void cov2b_kernel(const float* __restrict__ covf, u16* __restrict__ covb) {
    int i = blockIdx.x * 256 + threadIdx.x;        // w*CN*CN + c*CN + d   (c = B row = output-d, d = k)
    int w = i >> 18;
    int cd = i & ((1 << 18) - 1);
    int c = cd >> 9, d = cd & 511;
    int cb = c >> 7, db = d >> 7;
    size_t src;
    if (cb >= db) src = ((size_t)w << 18) + ((size_t)c << 9) + d;
    else          src = ((size_t)w << 18) + ((size_t)d << 9) + c;   // mirror from lower block
    float v = covf[src];
    if (c >= 256 && d < 256) v *= 2.f;     // fold symmetry weight into cross block
    covb[i] = f2b(v);
}

// ---------------- main: 128x128 tile, 4 waves, 3 blocks/CU, variable-K d-slice blocks ----------------
// One block per (m-tile, w, d-slice). With cross block pre-scaled 2x in covb:
//   d-slice 0: d=[0,128)   K=[0,256)  -> 8 chunks
//   d-slice 1: d=[128,256) K=[0,256)  -> 8 chunks
//   d-slice 2: d=[256,384) K=[0,512)  -> 16 chunks
//   d-slice 3: d=[384,512) K=[0,512)  -> 16 chunks
// 48 chunks per (m,w) (0.75x FLOPs) over 4 blocks -> 10400 blocks (r17-proven form).
__global__ __launch_bounds__(256, 3) void gemm128v_kernel(const u16* __restrict__ Abf,
                                                          const u16* __restrict__ covb,
                                                          float* __restrict__ simws) {
    __shared__ __align__(16) u16 As[2][128 * 32];
    __shared__ __align__(16) u16 Bs[2][128 * 32];
    __shared__ float simpart[128 * 3];

    int x = blockIdx.x & 7;
    int l = blockIdx.x >> 3;
    int g = l / 20;
    int m = x * 65 + g;
    if (m >= MT128) return;
    int inner = l - g * 20;
    int w  = inner % 5;
    int dsl = inner / 5;                 // 0..3
    int n0 = dsl * 128;
    int NCH = (dsl < 2) ? 8 : 16;        // K = 256 or 512
    int r0 = m * 128;

    int t = threadIdx.x;
    int lane = t & 63, wid = t >> 6;
    int wr = wid >> 1, wc = wid & 1;        // 2M x 2N waves, wave tile 64x64
    int rl = lane & 15, g4 = lane >> 4;
    int swz = ((rl >> 1) & 3) << 4;
    int kread = (g4 * 16) ^ swz;

    const char* gA = (const char*)(Abf + (size_t)r0 * CN);               // row stride 1024 B
    const char* gB = (const char*)(covb + ((size_t)w * CN + n0) * CN);   // row stride 1024 B

    f32x4 acc[4][4];
    #pragma unroll
    for (int mi = 0; mi < 4; ++mi)
        #pragma unroll
        for (int ni = 0; ni < 4; ++ni)
            acc[mi][ni] = (f32x4){0.f, 0.f, 0.f, 0.f};

    // stage chunk kc into slot kc&1: 2 A + 2 B gload16 per thread (8 KB each op)
    auto stage_chunk = [&](int kc) {
        int slot = kc & 1;
        int kbyte = kc * 64;
        #pragma unroll
        for (int j = 0; j < 2; ++j) {
            int off = j * 4096 + t * 16;
            int row = off >> 6;
            int kbs = (off & 63) ^ (((row >> 1) & 3) << 4);
            gload16(gA + (size_t)row * 1024 + kbyte + kbs, (char*)&As[slot][0] + off);
            gload16(gB + (size_t)row * 1024 + kbyte + kbs, (char*)&Bs[slot][0] + off);
        }
    };

    // merged chunk body (r14-proven): 8 ds_reads (b/a interleaved) then 16 MFMA
    auto do_chunk = [&](int c) {
        const char* Ab = (const char*)&As[c & 1][0];
        const char* Bb = (const char*)&Bs[c & 1][0];
        short8 a[4], b[4];
        #pragma unroll
        for (int ni = 0; ni < 4; ++ni) {
            b[ni] = *(const short8*)(Bb + (wc * 64 + ni * 16 + rl) * 64 + kread);
            a[ni] = *(const short8*)(Ab + (wr * 64 + ni * 16 + rl) * 64 + kread);
        }
        __builtin_amdgcn_s_setprio(1);
        #pragma unroll
        for (int mi = 0; mi < 4; ++mi)
            #pragma unroll
            for (int ni = 0; ni < 4; ++ni)
                acc[mi][ni] = __builtin_amdgcn_mfma_f32_16x16x32_bf16(
                    a[mi], b[ni], acc[mi][ni], 0, 0, 0);
        __builtin_amdgcn_s_setprio(0);
        // reads retired before MFMAs issued -> next top barrier closes this slot
    };

    stage_chunk(0);

    #pragma unroll 1
    for (int c = 0; c < NCH; ++c) {
        asm volatile("s_waitcnt vmcnt(0)" ::: "memory");   // chunk-c loads landed
        __builtin_amdgcn_s_barrier();
        asm volatile("" ::: "memory");
        if (c + 1 < NCH) stage_chunk(c + 1);               // depth-1 prefetch into other slot
        do_chunk(c);
    }

    // epilogue: partial sim over this block's 128 d-columns
    __syncthreads();
    #pragma unroll
    for (int mi = 0; mi < 4; ++mi) {
        #pragma unroll
        for (int r = 0; r < 4; ++r) {
            int Rl = wr * 64 + mi * 16 + g4 * 4 + r;
            size_t Rg = (size_t)r0 + Rl;
            float s = 0.f;
            #pragma unroll
            for (int ni = 0; ni < 4; ++ni) {
                int d = n0 + wc * 64 + ni * 16 + rl;
                s += acc[mi][ni][r] * b2f(Abf[Rg * CN + d]);
            }
            s += __shfl_xor(s, 1);
            s += __shfl_xor(s, 2);
            s += __shfl_xor(s, 4);
            s += __shfl_xor(s, 8);
            if (rl == 0) simpart[Rl * 3 + wc] = s;
        }
    }
    __syncthreads();
    if (t < 128) {
        float v = simpart[t * 3 + 0] + simpart[t * 3 + 1];
        atomicAdd(&simws[(size_t)w * MPAD2 + r0 + t], v);
    }
}

// ---------------- finish: act + conv dot + bias -> scores ----------------
__global__ void finish_kernel(const float* __restrict__ simws,
                              const float* __restrict__ conv_w,
                              const float* __restrict__ conv_b,
                              float* __restrict__ scores) {
    int q = blockIdx.x, w = blockIdx.y;
    int t = threadIdx.x;    // 128
    const float* sp = simws + (size_t)w * MPAD2 + q * HWN;
    float s = 0.f;
    for (int i = t; i < HWN; i += 128) {
        float v = sp[i];
        float a = (v >= 0.f) ? v : 0.2f * v;
        s += a * conv_w[i];
    }
    __shared__ float red[2];
    #pragma unroll
    for (int off = 32; off > 0; off >>= 1) s += __shfl_down(s, off);
    if ((t & 63) == 0) red[t >> 6] = s;
    __syncthreads();
    if (t == 0) scores[q * WAYN + w] = red[0] + red[1] + conv_b[0];
}

extern "C" void kernel_launch(void* const* d_in, const int* in_sizes, int n_in,
                              void* d_out, int out_size, void* d_ws, size_t ws_size,
                              hipStream_t stream) {
    const float* x1     = (const float*)d_in[0];
    const float* x2     = (const float*)d_in[1];
    const float* conv_w = (const float*)d_in[2];
    const float* conv_b = (const float*)d_in[3];
    float* scores = (float*)d_out;

    char* ws = (char*)d_ws;
    u16* covb    = (u16*)ws;                               // 2,621,440 B
    float* simws = (float*)(ws + 2631680);                 // 1,326,080 B
    float* covf  = (float*)(ws + 3957760);                 // 5,242,880 B
    // x2c aliases head of Abf (prep2's covmfma reads x2c while its qtrans writes Abf:
    // NOT aliasable anymore -> give x2c its own region)
    u16* x2c     = (u16*)(ws + 9200640);                   // 11,304,960 B
    u16* Abf     = (u16*)(ws + 20505600);                  // 66304*512*2 = 67,895,296 B  (ends ~88.4 MB)

    prep1_kernel<<<896, 256, 0, stream>>>(x2, x2c, simws, covf, (u32*)(Abf + (size_t)MROWS * CN));
    prep2_kernel<<<1500, 256, 0, stream>>>(x2c, covf, x1, Abf);
    cov2b_kernel<<<WAYN * CN * CN / 256, 256, 0, stream>>>(covf, covb);
    gemm128v_kernel<<<8 * 65 * 20, 256, 0, stream>>>(Abf, covb, simws);
    finish_kernel<<<dim3(QN, WAYN), 128, 0, stream>>>(simws, conv_w, conv_b, scores);
}

// Round 20
// 251.396 us; speedup vs baseline: 1.1408x; 1.0785x over previous
//
#include <hip/hip_runtime.h>
#include <hip/hip_bf16.h>

#define QN 150
#define CN 512
#define HWN 441
#define WAYN 5
#define SHOTN 5
#define NSAMP 2205           // SHOT*HW
#define MROWS (QN * HWN)     // 66150 packed rows
#define MT128 517            // ceil(66150/128)
#define MPAD2 66304
#define KP 2208              // cov K padded (32*69)
#define KPB (KP * 2)         // row bytes of x2c

typedef unsigned short u16;
typedef unsigned int u32;
typedef __attribute__((ext_vector_type(8))) short short8;
typedef __attribute__((ext_vector_type(4))) float f32x4;

__device__ __forceinline__ u16 f2b(float f) {
    return __builtin_bit_cast(u16, __float2bfloat16(f));
}
__device__ __forceinline__ float b2f(u16 h) {
    u32 u = ((u32)h) << 16;
    return __builtin_bit_cast(float, u);
}

__device__ __forceinline__ void gload16(const void* g, void* l) {
    __builtin_amdgcn_global_load_lds(
        (const __attribute__((address_space(1))) unsigned int*)g,
        (__attribute__((address_space(3))) unsigned int*)l, 16, 0, 0);
}

// pair index p in [0,10) -> (lo, hi) with lo <= hi over 4 blocks of 128
__device__ __forceinline__ void pair_decode(int p, int& lo, int& hi) {
    hi = (p >= 6) ? 3 : (p >= 3 ? 2 : (p >= 1 ? 1 : 0));
    int tri = (hi == 3) ? 6 : (hi == 2 ? 3 : (hi == 1 ? 1 : 0));
    lo = p - tri;
}

// ---------------- prep1 (fused): wx2c (blocks 0..639, 4 (w,c)/block) + zero-init (blocks 640..895) ----------------
__global__ __launch_bounds__(256) void prep1_kernel(const float* __restrict__ x2,
                                                    u16* __restrict__ x2c,
                                                    float* __restrict__ simws,
                                                    float* __restrict__ covf,
                                                    u32* __restrict__ AbfPad32) {
    int t = threadIdx.x;
    if (blockIdx.x < 640) {
        int lane = t & 63, sub = t >> 6;
        int b = blockIdx.x * 4 + sub;   // w*512 + c
        int w = b >> 9, c = b & 511;
        float s = 0.f;
        #pragma unroll
        for (int sh = 0; sh < SHOTN; ++sh) {
            const float* p = x2 + ((size_t)((w * SHOTN + sh) * CN + c)) * HWN;
            for (int i = lane; i < HWN; i += 64) s += p[i];
        }
        #pragma unroll
        for (int off = 32; off > 0; off >>= 1) s += __shfl_down(s, off);
        float m = __shfl(s, 0) * (1.0f / NSAMP);

        u16* dst = x2c + ((size_t)(w * CN + c)) * KP;
        #pragma unroll
        for (int sh = 0; sh < SHOTN; ++sh) {
            const float* p = x2 + ((size_t)((w * SHOTN + sh) * CN + c)) * HWN;
            for (int i = lane; i < HWN; i += 64) dst[sh * HWN + i] = f2b(p[i] - m);
        }
        if (lane < (KP - NSAMP)) dst[NSAMP + lane] = 0;
    } else {
        int tid = (blockIdx.x - 640) * 256 + t;
        int stride = 256 * 256;
        int nsim = WAYN * MPAD2;
        for (int i = tid; i < nsim; i += stride) simws[i] = 0.f;
        int ncov = WAYN * CN * CN;
        for (int i = tid; i < ncov; i += stride) covf[i] = 0.f;
        int npadw = (MPAD2 - MROWS) * CN / 2;
        for (int i = tid; i < npadw; i += stride) AbfPad32[i] = 0;
    }
}

// ---------------- prep2 (fused, heterogeneous): covmfma (blocks 0..299) || qtrans (blocks 300..1499) ----------------
__global__ __launch_bounds__(256, 2) void prep2_kernel(const u16* __restrict__ x2c,
                                                       float* __restrict__ covf,
                                                       const float* __restrict__ x1,
                                                       u16* __restrict__ Abf) {
    __shared__ __align__(16) char smem[73984];
    int t = threadIdx.x;

    if (blockIdx.x < 300) {
        // ======== covmfma role: split-K(6), lower-triangle 128-blocks ========
        u16* As0 = (u16*)smem;                    // [2][128*32]
        u16* Bs0 = (u16*)(smem + 16384);
        int bid = blockIdx.x;
        int z = bid / 10;
        int pr = bid - z * 10;
        int w  = z / 6, ksp = z - w * 6;
        int kchunks = (ksp < 3) ? 12 : 11;
        int kcoff   = (ksp < 3) ? ksp * 12 : 36 + (ksp - 3) * 11;
        int dblk, cblk;
        pair_decode(pr, dblk, cblk);    // cblk >= dblk
        int c0 = cblk * 128;
        int d0 = dblk * 128;
        int lane = t & 63, wid = t >> 6;
        int wr = wid >> 1, wc = wid & 1;
        int rl = lane & 15, g4 = lane >> 4;
        int swz = ((rl >> 1) & 3) << 4;
        int s0 = wid * 2048 + lane * 16;

        const char* gX = (const char*)(x2c + (size_t)w * CN * KP) + kcoff * 64;

        f32x4 acc[4][4];
        #pragma unroll
        for (int mi = 0; mi < 4; ++mi)
            #pragma unroll
            for (int ni = 0; ni < 4; ++ni)
                acc[mi][ni] = (f32x4){0.f, 0.f, 0.f, 0.f};

        int buf = 0;
        #pragma unroll
        for (int j = 0; j < 2; ++j) {
            int s = s0 + j * 1024;
            int row = s >> 6, kbs = (s & 63) ^ (((row >> 1) & 3) << 4);
            gload16(gX + (size_t)(c0 + row) * KPB + kbs, (char*)As0 + wid * 2048 + j * 1024);
            gload16(gX + (size_t)(d0 + row) * KPB + kbs, (char*)Bs0 + wid * 2048 + j * 1024);
        }
        __syncthreads();

        for (int ks = 0; ks < kchunks; ++ks) {
            if (ks < kchunks - 1) {
                int koff = (ks + 1) * 64;
                #pragma unroll
                for (int j = 0; j < 2; ++j) {
                    int s = s0 + j * 1024;
                    int row = s >> 6, kbs = (s & 63) ^ (((row >> 1) & 3) << 4);
                    gload16(gX + (size_t)(c0 + row) * KPB + koff + kbs,
                            (char*)As0 + (buf ^ 1) * 8192 + wid * 2048 + j * 1024);
                    gload16(gX + (size_t)(d0 + row) * KPB + koff + kbs,
                            (char*)Bs0 + (buf ^ 1) * 8192 + wid * 2048 + j * 1024);
                }
            }
            const char* Ab = (const char*)As0 + buf * 8192;
            const char* Bb = (const char*)Bs0 + buf * 8192;
            int kread = (g4 * 16) ^ swz;
            short8 a[4], b[4];
            #pragma unroll
            for (int mi = 0; mi < 4; ++mi)
                a[mi] = *(const short8*)(Ab + (wr * 64 + mi * 16 + rl) * 64 + kread);
            #pragma unroll
            for (int ni = 0; ni < 4; ++ni)
                b[ni] = *(const short8*)(Bb + (wc * 64 + ni * 16 + rl) * 64 + kread);
            #pragma unroll
            for (int mi = 0; mi < 4; ++mi)
                #pragma unroll
                for (int ni = 0; ni < 4; ++ni)
                    acc[mi][ni] = __builtin_amdgcn_mfma_f32_16x16x32_bf16(
                        a[mi], b[ni], acc[mi][ni], 0, 0, 0);
            __syncthreads();
            buf ^= 1;
        }

        const float inv = 1.0f / (NSAMP - 1);
        #pragma unroll
        for (int mi = 0; mi < 4; ++mi)
            #pragma unroll
            for (int r = 0; r < 4; ++r) {
                int c = c0 + wr * 64 + mi * 16 + g4 * 4 + r;
                #pragma unroll
                for (int ni = 0; ni < 4; ++ni) {
                    int d = d0 + wc * 64 + ni * 16 + rl;
                    atomicAdd(&covf[((size_t)w * CN + c) * CN + d], acc[mi][ni][r] * inv);
                }
            }
    } else {
        // ======== qtrans role ========
        u16 (*S)[72] = (u16(*)[72])smem;            // [512][72]
        float* qm = (float*)(smem + 73728);         // [64]
        int qb = blockIdx.x - 300;
        int c0 = (qb & 7) * 64;
        int q  = qb >> 3;
        int lane = t & 63, cq = t >> 6;

        for (int cc = cq; cc < 64; cc += 4) {
            int c = c0 + cc;
            const float* p = x1 + ((size_t)q * CN + c) * HWN;
            float s = 0.f;
            for (int ic = 0; ic < 8; ++ic) {
                int i = ic * 64 + lane;
                float v = (i < HWN) ? p[i] : 0.f;
                s += v;
                S[i][cc] = f2b(v);
            }
            #pragma unroll
            for (int off = 32; off > 0; off >>= 1) s += __shfl_down(s, off);
            if (lane == 0) qm[cc] = s * (1.0f / HWN);
        }
        __syncthreads();

        int coct = t & 7;
        for (int p = 0; p < 16; ++p) {
            int il = p * 32 + (t >> 3);
            if (il >= HWN) continue;
            short8 v = *(const short8*)(&S[il][coct * 8]);
            short8 o;
            #pragma unroll
            for (int j = 0; j < 8; ++j) {
                float f = b2f((u16)v[j]) - qm[coct * 8 + j];
                o[j] = (short)f2b(f);
            }
            *(short8*)(Abf + ((size_t)(q * HWN + il)) * CN + c0 + coct * 8) = o;
        }
    }
}

// ---------------- covf -> covb bf16: lower-triangle(+diag) 128-blocks only; strict-lower x2 ----------------
// gemm d-slice j reads covb rows c in slice j with k < (j+1)*128, i.e. k-block <= c-block.
__global__ void cov2b_kernel(const float* __restrict__ covf, u16* __restrict__ covb) {
    int i = blockIdx.x * 256 + threadIdx.x;        // w*CN*CN + c*CN + d   (c = output-d row, d = k)
    int w = i >> 18;
    int cd = i & ((1 << 18) - 1);
    int c = cd >> 9, d = cd & 511;
    int cb = c >> 7, db = d >> 7;
    if (cb < db) return;                           // never read by gemm
    size_t src = ((size_t)w << 18) + ((size_t)c << 9) + d;   // cb>=db: direct (covf lower-tri valid)
    float v = covf[src];
    if (cb > db) v *= 2.f;                         // fold symmetry weight into strict-lower blocks
    covb[i] = f2b(v);
}

// ---------------- main: 128x128 tile, 4 waves, 3 blocks/CU, triangular variable-K d-slices ----------------
// One block per (m-tile, w, d-slice j). With strict-lower 128-blocks pre-scaled 2x in covb:
//   slice j: d=[j*128,(j+1)*128), K=[0,(j+1)*128) -> NCH = (j+1)*4 chunks
// Total 40 chunks per (m,w) = 0.625x full FLOPs. 10400 blocks (r17-proven form).
__global__ __launch_bounds__(256, 3) void gemm128v_kernel(const u16* __restrict__ Abf,
                                                          const u16* __restrict__ covb,
                                                          float* __restrict__ simws) {
    __shared__ __align__(16) u16 As[2][128 * 32];
    __shared__ __align__(16) u16 Bs[2][128 * 32];
    __shared__ float simpart[128 * 3];

    int x = blockIdx.x & 7;
    int l = blockIdx.x >> 3;
    int g = l / 20;
    int m = x * 65 + g;
    if (m >= MT128) return;
    int inner = l - g * 20;
    int w  = inner % 5;
    int dsl = inner / 5;                 // 0..3
    int n0 = dsl * 128;
    int NCH = (dsl + 1) * 4;             // K = (dsl+1)*128
    int r0 = m * 128;

    int t = threadIdx.x;
    int lane = t & 63, wid = t >> 6;
    int wr = wid >> 1, wc = wid & 1;        // 2M x 2N waves, wave tile 64x64
    int rl = lane & 15, g4 = lane >> 4;
    int swz = ((rl >> 1) & 3) << 4;
    int kread = (g4 * 16) ^ swz;

    const char* gA = (const char*)(Abf + (size_t)r0 * CN);               // row stride 1024 B
    const char* gB = (const char*)(covb + ((size_t)w * CN + n0) * CN);   // row stride 1024 B

    f32x4 acc[4][4];
    #pragma unroll
    for (int mi = 0; mi < 4; ++mi)
        #pragma unroll
        for (int ni = 0; ni < 4; ++ni)
            acc[mi][ni] = (f32x4){0.f, 0.f, 0.f, 0.f};

    // stage chunk kc into slot kc&1: 2 A + 2 B gload16 per thread (8 KB each op)
    auto stage_chunk = [&](int kc) {
        int slot = kc & 1;
        int kbyte = kc * 64;
        #pragma unroll
        for (int j = 0; j < 2; ++j) {
            int off = j * 4096 + t * 16;
            int row = off >> 6;
            int kbs = (off & 63) ^ (((row >> 1) & 3) << 4);
            gload16(gA + (size_t)row * 1024 + kbyte + kbs, (char*)&As[slot][0] + off);
            gload16(gB + (size_t)row * 1024 + kbyte + kbs, (char*)&Bs[slot][0] + off);
        }
    };

    // merged chunk body (r14-proven): 8 ds_reads (b/a interleaved) then 16 MFMA
    auto do_chunk = [&](int c) {
        const char* Ab = (const char*)&As[c & 1][0];
        const char* Bb = (const char*)&Bs[c & 1][0];
        short8 a[4], b[4];
        #pragma unroll
        for (int ni = 0; ni < 4; ++ni) {
            b[ni] = *(const short8*)(Bb + (wc * 64 + ni * 16 + rl) * 64 + kread);
            a[ni] = *(const short8*)(Ab + (wr * 64 + ni * 16 + rl) * 64 + kread);
        }
        __builtin_amdgcn_s_setprio(1);
        #pragma unroll
        for (int mi = 0; mi < 4; ++mi)
            #pragma unroll
            for (int ni = 0; ni < 4; ++ni)
                acc[mi][ni] = __builtin_amdgcn_mfma_f32_16x16x32_bf16(
                    a[mi], b[ni], acc[mi][ni], 0, 0, 0);
        __builtin_amdgcn_s_setprio(0);
        // reads retired before MFMAs issued -> next top barrier closes this slot
    };

    stage_chunk(0);

    #pragma unroll 1
    for (int c = 0; c < NCH; ++c) {
        asm volatile("s_waitcnt vmcnt(0)" ::: "memory");   // chunk-c loads landed
        __builtin_amdgcn_s_barrier();
        asm volatile("" ::: "memory");
        if (c + 1 < NCH) stage_chunk(c + 1);               // depth-1 prefetch into other slot
        do_chunk(c);
    }

    // epilogue: partial sim over this block's 128 d-columns
    __syncthreads();
    #pragma unroll
    for (int mi = 0; mi < 4; ++mi) {
        #pragma unroll
        for (int r = 0; r < 4; ++r) {
            int Rl = wr * 64 + mi * 16 + g4 * 4 + r;
            size_t Rg = (size_t)r0 + Rl;
            float s = 0.f;
            #pragma unroll
            for (int ni = 0; ni < 4; ++ni) {
                int d = n0 + wc * 64 + ni * 16 + rl;
                s += acc[mi][ni][r] * b2f(Abf[Rg * CN + d]);
            }
            s += __shfl_xor(s, 1);
            s += __shfl_xor(s, 2);
            s += __shfl_xor(s, 4);
            s += __shfl_xor(s, 8);
            if (rl == 0) simpart[Rl * 3 + wc] = s;
        }
    }
    __syncthreads();
    if (t < 128) {
        float v = simpart[t * 3 + 0] + simpart[t * 3 + 1];
        atomicAdd(&simws[(size_t)w * MPAD2 + r0 + t], v);
    }
}

// ---------------- finish: act + conv dot + bias -> scores ----------------
__global__ void finish_kernel(const float* __restrict__ simws,
                              const float* __restrict__ conv_w,
                              const float* __restrict__ conv_b,
                              float* __restrict__ scores) {
    int q = blockIdx.x, w = blockIdx.y;
    int t = threadIdx.x;    // 128
    const float* sp = simws + (size_t)w * MPAD2 + q * HWN;
    float s = 0.f;
    for (int i = t; i < HWN; i += 128) {
        float v = sp[i];
        float a = (v >= 0.f) ? v : 0.2f * v;
        s += a * conv_w[i];
    }
    __shared__ float red[2];
    #pragma unroll
    for (int off = 32; off > 0; off >>= 1) s += __shfl_down(s, off);
    if ((t & 63) == 0) red[t >> 6] = s;
    __syncthreads();
    if (t == 0) scores[q * WAYN + w] = red[0] + red[1] + conv_b[0];
}

extern "C" void kernel_launch(void* const* d_in, const int* in_sizes, int n_in,
                              void* d_out, int out_size, void* d_ws, size_t ws_size,
                              hipStream_t stream) {
    const float* x1     = (const float*)d_in[0];
    const float* x2     = (const float*)d_in[1];
    const float* conv_w = (const float*)d_in[2];
    const float* conv_b = (const float*)d_in[3];
    float* scores = (float*)d_out;

    char* ws = (char*)d_ws;
    u16* covb    = (u16*)ws;                               // 2,621,440 B
    float* simws = (float*)(ws + 2631680);                 // 1,326,080 B
    float* covf  = (float*)(ws + 3957760);                 // 5,242,880 B
    u16* x2c     = (u16*)(ws + 9200640);                   // 11,304,960 B (own region: prep2 overlap)
    u16* Abf     = (u16*)(ws + 20505600);                  // 66304*512*2 = 67,895,296 B

    prep1_kernel<<<896, 256, 0, stream>>>(x2, x2c, simws, covf, (u32*)(Abf + (size_t)MROWS * CN));
    prep2_kernel<<<1500, 256, 0, stream>>>(x2c, covf, x1, Abf);
    cov2b_kernel<<<WAYN * CN * CN / 256, 256, 0, stream>>>(covf, covb);
    gemm128v_kernel<<<8 * 65 * 20, 256, 0, stream>>>(Abf, covb, simws);
    finish_kernel<<<dim3(QN, WAYN), 128, 0, stream>>>(simws, conv_w, conv_b, scores);
}

// Round 21
// 245.894 us; speedup vs baseline: 1.1663x; 1.0224x over previous
//
#include <hip/hip_runtime.h>
#include <hip/hip_bf16.h>

#define QN 150
#define CN 512
#define HWN 441
#define WAYN 5
#define SHOTN 5
#define NSAMP 2205           // SHOT*HW
#define MROWS (QN * HWN)     // 66150 packed rows
#define MT128 517            // ceil(66150/128)
#define MPAD2 66304
#define KP 2208              // cov K padded (32*69)
#define KPB (KP * 2)         // row bytes of x2c

typedef unsigned short u16;
typedef unsigned int u32;
typedef __attribute__((ext_vector_type(8))) short short8;
typedef __attribute__((ext_vector_type(4))) float f32x4;

__device__ __forceinline__ u16 f2b(float f) {
    return __builtin_bit_cast(u16, __float2bfloat16(f));
}
__device__ __forceinline__ float b2f(u16 h) {
    u32 u = ((u32)h) << 16;
    return __builtin_bit_cast(float, u);
}

__device__ __forceinline__ void gload16(const void* g, void* l) {
    __builtin_amdgcn_global_load_lds(
        (const __attribute__((address_space(1))) unsigned int*)g,
        (__attribute__((address_space(3))) unsigned int*)l, 16, 0, 0);
}

// pair index p in [0,10) -> (lo, hi) with lo <= hi over 4 blocks of 128
__device__ __forceinline__ void pair_decode(int p, int& lo, int& hi) {
    hi = (p >= 6) ? 3 : (p >= 3 ? 2 : (p >= 1 ? 1 : 0));
    int tri = (hi == 3) ? 6 : (hi == 2 ? 3 : (hi == 1 ? 1 : 0));
    lo = p - tri;
}

// ---------------- prep1 (fused): wx2c (blocks 0..639, 4 (w,c)/block) + zero-init (blocks 640..895) ----------------
__global__ __launch_bounds__(256) void prep1_kernel(const float* __restrict__ x2,
                                                    u16* __restrict__ x2c,
                                                    float* __restrict__ simws,
                                                    float* __restrict__ covf,
                                                    u32* __restrict__ AbfPad32) {
    int t = threadIdx.x;
    if (blockIdx.x < 640) {
        int lane = t & 63, sub = t >> 6;
        int b = blockIdx.x * 4 + sub;   // w*512 + c
        int w = b >> 9, c = b & 511;
        float s = 0.f;
        #pragma unroll
        for (int sh = 0; sh < SHOTN; ++sh) {
            const float* p = x2 + ((size_t)((w * SHOTN + sh) * CN + c)) * HWN;
            for (int i = lane; i < HWN; i += 64) s += p[i];
        }
        #pragma unroll
        for (int off = 32; off > 0; off >>= 1) s += __shfl_down(s, off);
        float m = __shfl(s, 0) * (1.0f / NSAMP);

        u16* dst = x2c + ((size_t)(w * CN + c)) * KP;
        #pragma unroll
        for (int sh = 0; sh < SHOTN; ++sh) {
            const float* p = x2 + ((size_t)((w * SHOTN + sh) * CN + c)) * HWN;
            for (int i = lane; i < HWN; i += 64) dst[sh * HWN + i] = f2b(p[i] - m);
        }
        if (lane < (KP - NSAMP)) dst[NSAMP + lane] = 0;
    } else {
        int tid = (blockIdx.x - 640) * 256 + t;
        int stride = 256 * 256;
        int nsim = WAYN * MPAD2;
        for (int i = tid; i < nsim; i += stride) simws[i] = 0.f;
        int ncov = WAYN * CN * CN;
        for (int i = tid; i < ncov; i += stride) covf[i] = 0.f;
        int npadw = (MPAD2 - MROWS) * CN / 2;
        for (int i = tid; i < npadw; i += stride) AbfPad32[i] = 0;
    }
}

// ---------------- prep2 (fused, heterogeneous): covmfma (blocks 0..299) || qtrans (blocks 300..1499) ----------------
__global__ __launch_bounds__(256, 2) void prep2_kernel(const u16* __restrict__ x2c,
                                                       float* __restrict__ covf,
                                                       const float* __restrict__ x1,
                                                       u16* __restrict__ Abf) {
    __shared__ __align__(16) char smem[73984];
    int t = threadIdx.x;

    if (blockIdx.x < 300) {
        // ======== covmfma role: split-K(6), lower-triangle 128-blocks ========
        u16* As0 = (u16*)smem;                    // [2][128*32]
        u16* Bs0 = (u16*)(smem + 16384);
        int bid = blockIdx.x;
        int z = bid / 10;
        int pr = bid - z * 10;
        int w  = z / 6, ksp = z - w * 6;
        int kchunks = (ksp < 3) ? 12 : 11;
        int kcoff   = (ksp < 3) ? ksp * 12 : 36 + (ksp - 3) * 11;
        int dblk, cblk;
        pair_decode(pr, dblk, cblk);    // cblk >= dblk
        int c0 = cblk * 128;
        int d0 = dblk * 128;
        int lane = t & 63, wid = t >> 6;
        int wr = wid >> 1, wc = wid & 1;
        int rl = lane & 15, g4 = lane >> 4;
        int swz = ((rl >> 1) & 3) << 4;
        int s0 = wid * 2048 + lane * 16;

        const char* gX = (const char*)(x2c + (size_t)w * CN * KP) + kcoff * 64;

        f32x4 acc[4][4];
        #pragma unroll
        for (int mi = 0; mi < 4; ++mi)
            #pragma unroll
            for (int ni = 0; ni < 4; ++ni)
                acc[mi][ni] = (f32x4){0.f, 0.f, 0.f, 0.f};

        int buf = 0;
        #pragma unroll
        for (int j = 0; j < 2; ++j) {
            int s = s0 + j * 1024;
            int row = s >> 6, kbs = (s & 63) ^ (((row >> 1) & 3) << 4);
            gload16(gX + (size_t)(c0 + row) * KPB + kbs, (char*)As0 + wid * 2048 + j * 1024);
            gload16(gX + (size_t)(d0 + row) * KPB + kbs, (char*)Bs0 + wid * 2048 + j * 1024);
        }
        __syncthreads();

        for (int ks = 0; ks < kchunks; ++ks) {
            if (ks < kchunks - 1) {
                int koff = (ks + 1) * 64;
                #pragma unroll
                for (int j = 0; j < 2; ++j) {
                    int s = s0 + j * 1024;
                    int row = s >> 6, kbs = (s & 63) ^ (((row >> 1) & 3) << 4);
                    gload16(gX + (size_t)(c0 + row) * KPB + koff + kbs,
                            (char*)As0 + (buf ^ 1) * 8192 + wid * 2048 + j * 1024);
                    gload16(gX + (size_t)(d0 + row) * KPB + koff + kbs,
                            (char*)Bs0 + (buf ^ 1) * 8192 + wid * 2048 + j * 1024);
                }
            }
            const char* Ab = (const char*)As0 + buf * 8192;
            const char* Bb = (const char*)Bs0 + buf * 8192;
            int kread = (g4 * 16) ^ swz;
            short8 a[4], b[4];
            #pragma unroll
            for (int mi = 0; mi < 4; ++mi)
                a[mi] = *(const short8*)(Ab + (wr * 64 + mi * 16 + rl) * 64 + kread);
            #pragma unroll
            for (int ni = 0; ni < 4; ++ni)
                b[ni] = *(const short8*)(Bb + (wc * 64 + ni * 16 + rl) * 64 + kread);
            #pragma unroll
            for (int mi = 0; mi < 4; ++mi)
                #pragma unroll
                for (int ni = 0; ni < 4; ++ni)
                    acc[mi][ni] = __builtin_amdgcn_mfma_f32_16x16x32_bf16(
                        a[mi], b[ni], acc[mi][ni], 0, 0, 0);
            __syncthreads();
            buf ^= 1;
        }

        const float inv = 1.0f / (NSAMP - 1);
        #pragma unroll
        for (int mi = 0; mi < 4; ++mi)
            #pragma unroll
            for (int r = 0; r < 4; ++r) {
                int c = c0 + wr * 64 + mi * 16 + g4 * 4 + r;
                #pragma unroll
                for (int ni = 0; ni < 4; ++ni) {
                    int d = d0 + wc * 64 + ni * 16 + rl;
                    atomicAdd(&covf[((size_t)w * CN + c) * CN + d], acc[mi][ni][r] * inv);
                }
            }
    } else {
        // ======== qtrans role ========
        u16 (*S)[72] = (u16(*)[72])smem;            // [512][72]
        float* qm = (float*)(smem + 73728);         // [64]
        int qb = blockIdx.x - 300;
        int c0 = (qb & 7) * 64;
        int q  = qb >> 3;
        int lane = t & 63, cq = t >> 6;

        for (int cc = cq; cc < 64; cc += 4) {
            int c = c0 + cc;
            const float* p = x1 + ((size_t)q * CN + c) * HWN;
            float s = 0.f;
            for (int ic = 0; ic < 8; ++ic) {
                int i = ic * 64 + lane;
                float v = (i < HWN) ? p[i] : 0.f;
                s += v;
                S[i][cc] = f2b(v);
            }
            #pragma unroll
            for (int off = 32; off > 0; off >>= 1) s += __shfl_down(s, off);
            if (lane == 0) qm[cc] = s * (1.0f / HWN);
        }
        __syncthreads();

        int coct = t & 7;
        for (int p = 0; p < 16; ++p) {
            int il = p * 32 + (t >> 3);
            if (il >= HWN) continue;
            short8 v = *(const short8*)(&S[il][coct * 8]);
            short8 o;
            #pragma unroll
            for (int j = 0; j < 8; ++j) {
                float f = b2f((u16)v[j]) - qm[coct * 8 + j];
                o[j] = (short)f2b(f);
            }
            *(short8*)(Abf + ((size_t)(q * HWN + il)) * CN + c0 + coct * 8) = o;
        }
    }
}

// ---------------- covf -> covb bf16: lower-triangle(+diag) 128-blocks only; strict-lower x2 ----------------
__global__ void cov2b_kernel(const float* __restrict__ covf, u16* __restrict__ covb) {
    int i = blockIdx.x * 256 + threadIdx.x;        // w*CN*CN + c*CN + d   (c = output-d row, d = k)
    int w = i >> 18;
    int cd = i & ((1 << 18) - 1);
    int c = cd >> 9, d = cd & 511;
    int cb = c >> 7, db = d >> 7;
    if (cb < db) return;                           // never read by gemm
    size_t src = ((size_t)w << 18) + ((size_t)c << 9) + d;
    float v = covf[src];
    if (cb > db) v *= 2.f;                         // fold symmetry weight into strict-lower blocks
    covb[i] = f2b(v);
}

// ---------------- main: 128x128 tile, 4 waves, 3 blocks/CU, paired triangular d-slices ----------------
// Per (m,w): TWO balanced 20-chunk blocks (strict-lower covb blocks pre-scaled 2x):
//   ps=0: slice0 (d=[0,128),   K=[0,128),  4 ch) then slice3 (d=[384,512), K=[0,512), 16 ch)
//   ps=1: slice1 (d=[128,256), K=[0,256),  8 ch) then slice2 (d=[256,384), K=[0,384), 12 ch)
// One register-local drain at the slice boundary (r16-proven), one final reduce+atomicAdd.
// 5200 blocks x 20 chunks = 104000 chunks (0.625x FLOPs) with half the per-block overhead of r20.
__global__ __launch_bounds__(256, 3) void gemm128p_kernel(const u16* __restrict__ Abf,
                                                          const u16* __restrict__ covb,
                                                          float* __restrict__ simws) {
    __shared__ __align__(16) u16 As[2][128 * 32];
    __shared__ __align__(16) u16 Bs[2][128 * 32];
    __shared__ float simpart[128 * 3];

    int x = blockIdx.x & 7;
    int l = blockIdx.x >> 3;
    int g = l / 10;
    int m = x * 65 + g;
    if (m >= MT128) return;
    int inner = l - g * 10;
    int w  = inner % 5;
    int ps = inner / 5;                   // 0: {slice0, slice3}; 1: {slice1, slice2}
    int bnd   = (ps == 0) ? 4 : 8;        // chunk boundary between the two slices
    int dslA  = (ps == 0) ? 0 : 1;
    int dslB  = (ps == 0) ? 3 : 2;
    int r0 = m * 128;

    int t = threadIdx.x;
    int lane = t & 63, wid = t >> 6;
    int wr = wid >> 1, wc = wid & 1;        // 2M x 2N waves, wave tile 64x64
    int rl = lane & 15, g4 = lane >> 4;
    int swz = ((rl >> 1) & 3) << 4;
    int kread = (g4 * 16) ^ swz;

    const char* gA  = (const char*)(Abf + (size_t)r0 * CN);                      // row stride 1024 B
    const char* gBA = (const char*)(covb + ((size_t)w * CN + dslA * 128) * CN);  // slice-A B rows
    const char* gBB = (const char*)(covb + ((size_t)w * CN + dslB * 128) * CN);  // slice-B B rows

    f32x4 acc[4][4];
    float simreg[16];
    #pragma unroll
    for (int i = 0; i < 16; ++i) simreg[i] = 0.f;
    #pragma unroll
    for (int mi = 0; mi < 4; ++mi)
        #pragma unroll
        for (int ni = 0; ni < 4; ++ni)
            acc[mi][ni] = (f32x4){0.f, 0.f, 0.f, 0.f};

    // stage global chunk gc into slot gc&1: 2 A + 2 B gload16 per thread
    auto stage_chunk = [&](int gc) {
        bool second = (gc >= bnd);
        const char* gB = second ? gBB : gBA;
        int kbyte = (second ? (gc - bnd) : gc) * 64;
        int slot = gc & 1;
        #pragma unroll
        for (int j = 0; j < 2; ++j) {
            int off = j * 4096 + t * 16;
            int row = off >> 6;
            int kbs = (off & 63) ^ (((row >> 1) & 3) << 4);
            gload16(gA + (size_t)row * 1024 + kbyte + kbs, (char*)&As[slot][0] + off);
            gload16(gB + (size_t)row * 1024 + kbyte + kbs, (char*)&Bs[slot][0] + off);
        }
    };

    // merged chunk body (r14-proven): 8 ds_reads (b/a interleaved) then 16 MFMA
    auto do_chunk = [&](int gc) {
        const char* Ab = (const char*)&As[gc & 1][0];
        const char* Bb = (const char*)&Bs[gc & 1][0];
        short8 a[4], b[4];
        #pragma unroll
        for (int ni = 0; ni < 4; ++ni) {
            b[ni] = *(const short8*)(Bb + (wc * 64 + ni * 16 + rl) * 64 + kread);
            a[ni] = *(const short8*)(Ab + (wr * 64 + ni * 16 + rl) * 64 + kread);
        }
        __builtin_amdgcn_s_setprio(1);
        #pragma unroll
        for (int mi = 0; mi < 4; ++mi)
            #pragma unroll
            for (int ni = 0; ni < 4; ++ni)
                acc[mi][ni] = __builtin_amdgcn_mfma_f32_16x16x32_bf16(
                    a[mi], b[ni], acc[mi][ni], 0, 0, 0);
        __builtin_amdgcn_s_setprio(0);
    };

    // register-local sub-pass drain (r16-proven): rowdot acc with centered-q, reset acc
    auto drain = [&](int db) {
        #pragma unroll
        for (int mi = 0; mi < 4; ++mi) {
            #pragma unroll
            for (int r = 0; r < 4; ++r) {
                int Rl = wr * 64 + mi * 16 + g4 * 4 + r;
                size_t Rg = (size_t)r0 + Rl;
                float s = 0.f;
                #pragma unroll
                for (int ni = 0; ni < 4; ++ni) {
                    int d = db + wc * 64 + ni * 16 + rl;
                    s += acc[mi][ni][r] * b2f(Abf[Rg * CN + d]);
                }
                simreg[mi * 4 + r] += s;
            }
        }
        #pragma unroll
        for (int mi = 0; mi < 4; ++mi)
            #pragma unroll
            for (int ni = 0; ni < 4; ++ni)
                acc[mi][ni] = (f32x4){0.f, 0.f, 0.f, 0.f};
    };

    stage_chunk(0);

    #pragma unroll 1
    for (int gc = 0; gc < 20; ++gc) {
        asm volatile("s_waitcnt vmcnt(0)" ::: "memory");   // chunk-gc loads landed
        __builtin_amdgcn_s_barrier();
        asm volatile("" ::: "memory");
        if (gc < 19) stage_chunk(gc + 1);                  // depth-1 prefetch into other slot
        do_chunk(gc);
        if (gc == bnd - 1) drain(dslA * 128);              // slice-A done (prefetch of slice-B already in flight)
    }
    drain(dslB * 128);                                     // slice-B done

    // final reduce: simreg over 16-lane groups -> simpart -> atomicAdd
    #pragma unroll
    for (int idx = 0; idx < 16; ++idx) {
        float v = simreg[idx];
        v += __shfl_xor(v, 1);
        v += __shfl_xor(v, 2);
        v += __shfl_xor(v, 4);
        v += __shfl_xor(v, 8);
        int mi = idx >> 2, r = idx & 3;
        int Rl = wr * 64 + mi * 16 + g4 * 4 + r;
        if (rl == 0) simpart[Rl * 3 + wc] = v;
    }
    __syncthreads();
    if (t < 128) {
        float v = simpart[t * 3 + 0] + simpart[t * 3 + 1];
        atomicAdd(&simws[(size_t)w * MPAD2 + r0 + t], v);
    }
}

// ---------------- finish: act + conv dot + bias -> scores ----------------
__global__ void finish_kernel(const float* __restrict__ simws,
                              const float* __restrict__ conv_w,
                              const float* __restrict__ conv_b,
                              float* __restrict__ scores) {
    int q = blockIdx.x, w = blockIdx.y;
    int t = threadIdx.x;    // 128
    const float* sp = simws + (size_t)w * MPAD2 + q * HWN;
    float s = 0.f;
    for (int i = t; i < HWN; i += 128) {
        float v = sp[i];
        float a = (v >= 0.f) ? v : 0.2f * v;
        s += a * conv_w[i];
    }
    __shared__ float red[2];
    #pragma unroll
    for (int off = 32; off > 0; off >>= 1) s += __shfl_down(s, off);
    if ((t & 63) == 0) red[t >> 6] = s;
    __syncthreads();
    if (t == 0) scores[q * WAYN + w] = red[0] + red[1] + conv_b[0];
}

extern "C" void kernel_launch(void* const* d_in, const int* in_sizes, int n_in,
                              void* d_out, int out_size, void* d_ws, size_t ws_size,
                              hipStream_t stream) {
    const float* x1     = (const float*)d_in[0];
    const float* x2     = (const float*)d_in[1];
    const float* conv_w = (const float*)d_in[2];
    const float* conv_b = (const float*)d_in[3];
    float* scores = (float*)d_out;

    char* ws = (char*)d_ws;
    u16* covb    = (u16*)ws;                               // 2,621,440 B
    float* simws = (float*)(ws + 2631680);                 // 1,326,080 B
    float* covf  = (float*)(ws + 3957760);                 // 5,242,880 B
    u16* x2c     = (u16*)(ws + 9200640);                   // 11,304,960 B (own region: prep2 overlap)
    u16* Abf     = (u16*)(ws + 20505600);                  // 66304*512*2 = 67,895,296 B

    prep1_kernel<<<896, 256, 0, stream>>>(x2, x2c, simws, covf, (u32*)(Abf + (size_t)MROWS * CN));
    prep2_kernel<<<1500, 256, 0, stream>>>(x2c, covf, x1, Abf);
    cov2b_kernel<<<WAYN * CN * CN / 256, 256, 0, stream>>>(covf, covb);
    gemm128p_kernel<<<8 * 65 * 10, 256, 0, stream>>>(Abf, covb, simws);
    finish_kernel<<<dim3(QN, WAYN), 128, 0, stream>>>(simws, conv_w, conv_b, scores);
}

// Round 22
// 234.858 us; speedup vs baseline: 1.2211x; 1.0470x over previous
//
#include <hip/hip_runtime.h>
#include <hip/hip_bf16.h>

#define QN 150
#define CN 512
#define HWN 441
#define WAYN 5
#define SHOTN 5
#define NSAMP 2205           // SHOT*HW
#define MROWS (QN * HWN)     // 66150 packed rows
#define MT128 517            // ceil(66150/128)
#define MPAD2 66304
#define KP 2208              // cov K padded (32*69)
#define KPB (KP * 2)         // row bytes of x2c

typedef unsigned short u16;
typedef unsigned int u32;
typedef __attribute__((ext_vector_type(8))) short short8;
typedef __attribute__((ext_vector_type(4))) float f32x4;

__device__ __forceinline__ u16 f2b(float f) {
    return __builtin_bit_cast(u16, __float2bfloat16(f));
}
__device__ __forceinline__ float b2f(u16 h) {
    u32 u = ((u32)h) << 16;
    return __builtin_bit_cast(float, u);
}

__device__ __forceinline__ void gload16(const void* g, void* l) {
    __builtin_amdgcn_global_load_lds(
        (const __attribute__((address_space(1))) unsigned int*)g,
        (__attribute__((address_space(3))) unsigned int*)l, 16, 0, 0);
}

// pair index p in [0,10) -> (lo, hi) with lo <= hi over 4 blocks of 128
__device__ __forceinline__ void pair_decode(int p, int& lo, int& hi) {
    hi = (p >= 6) ? 3 : (p >= 3 ? 2 : (p >= 1 ? 1 : 0));
    int tri = (hi == 3) ? 6 : (hi == 2 ? 3 : (hi == 1 ? 1 : 0));
    lo = p - tri;
}

// ---------------- prep1 (fused): wx2c single-pass via LDS (blocks 0..639) + zero-init (640..895) ----------------
__global__ __launch_bounds__(256) void prep1_kernel(const float* __restrict__ x2,
                                                    u16* __restrict__ x2c,
                                                    float* __restrict__ simws,
                                                    float* __restrict__ covf,
                                                    u32* __restrict__ AbfPad32) {
    __shared__ float Sx[4][2208];    // per-wave x2 slice cache (single global read)
    int t = threadIdx.x;
    if (blockIdx.x < 640) {
        int lane = t & 63, sub = t >> 6;
        int b = blockIdx.x * 4 + sub;   // w*512 + c
        int w = b >> 9, c = b & 511;
        float s = 0.f;
        #pragma unroll
        for (int sh = 0; sh < SHOTN; ++sh) {
            const float* p = x2 + ((size_t)((w * SHOTN + sh) * CN + c)) * HWN;
            for (int i = lane; i < HWN; i += 64) {
                float v = p[i];
                Sx[sub][sh * HWN + i] = v;
                s += v;
            }
        }
        #pragma unroll
        for (int off = 32; off > 0; off >>= 1) s += __shfl_down(s, off);
        float m = __shfl(s, 0) * (1.0f / NSAMP);

        u16* dst = x2c + ((size_t)(w * CN + c)) * KP;
        for (int k = lane; k < NSAMP; k += 64) dst[k] = f2b(Sx[sub][k] - m);
        if (lane < (KP - NSAMP)) dst[NSAMP + lane] = 0;
    } else {
        int tid = (blockIdx.x - 640) * 256 + t;
        int stride = 256 * 256;
        int nsim = WAYN * MPAD2;
        for (int i = tid; i < nsim; i += stride) simws[i] = 0.f;
        int ncov = WAYN * CN * CN;
        for (int i = tid; i < ncov; i += stride) covf[i] = 0.f;
        int npadw = (MPAD2 - MROWS) * CN / 2;
        for (int i = tid; i < npadw; i += stride) AbfPad32[i] = 0;
    }
}

// ---------------- prep2 (fused, heterogeneous): covmfma (blocks 0..299) || qtrans (blocks 300..1499) ----------------
__global__ __launch_bounds__(256, 2) void prep2_kernel(const u16* __restrict__ x2c,
                                                       float* __restrict__ covf,
                                                       const float* __restrict__ x1,
                                                       u16* __restrict__ Abf) {
    __shared__ __align__(16) char smem[73984];
    int t = threadIdx.x;

    if (blockIdx.x < 300) {
        // ======== covmfma role: split-K(6), lower-triangle 128-blocks ========
        u16* As0 = (u16*)smem;                    // [2][128*32]
        u16* Bs0 = (u16*)(smem + 16384);
        int bid = blockIdx.x;
        int z = bid / 10;
        int pr = bid - z * 10;
        int w  = z / 6, ksp = z - w * 6;
        int kchunks = (ksp < 3) ? 12 : 11;
        int kcoff   = (ksp < 3) ? ksp * 12 : 36 + (ksp - 3) * 11;
        int dblk, cblk;
        pair_decode(pr, dblk, cblk);    // cblk >= dblk
        int c0 = cblk * 128;
        int d0 = dblk * 128;
        int lane = t & 63, wid = t >> 6;
        int wr = wid >> 1, wc = wid & 1;
        int rl = lane & 15, g4 = lane >> 4;
        int swz = ((rl >> 1) & 3) << 4;
        int s0 = wid * 2048 + lane * 16;

        const char* gX = (const char*)(x2c + (size_t)w * CN * KP) + kcoff * 64;

        f32x4 acc[4][4];
        #pragma unroll
        for (int mi = 0; mi < 4; ++mi)
            #pragma unroll
            for (int ni = 0; ni < 4; ++ni)
                acc[mi][ni] = (f32x4){0.f, 0.f, 0.f, 0.f};

        int buf = 0;
        #pragma unroll
        for (int j = 0; j < 2; ++j) {
            int s = s0 + j * 1024;
            int row = s >> 6, kbs = (s & 63) ^ (((row >> 1) & 3) << 4);
            gload16(gX + (size_t)(c0 + row) * KPB + kbs, (char*)As0 + wid * 2048 + j * 1024);
            gload16(gX + (size_t)(d0 + row) * KPB + kbs, (char*)Bs0 + wid * 2048 + j * 1024);
        }
        __syncthreads();

        for (int ks = 0; ks < kchunks; ++ks) {
            if (ks < kchunks - 1) {
                int koff = (ks + 1) * 64;
                #pragma unroll
                for (int j = 0; j < 2; ++j) {
                    int s = s0 + j * 1024;
                    int row = s >> 6, kbs = (s & 63) ^ (((row >> 1) & 3) << 4);
                    gload16(gX + (size_t)(c0 + row) * KPB + koff + kbs,
                            (char*)As0 + (buf ^ 1) * 8192 + wid * 2048 + j * 1024);
                    gload16(gX + (size_t)(d0 + row) * KPB + koff + kbs,
                            (char*)Bs0 + (buf ^ 1) * 8192 + wid * 2048 + j * 1024);
                }
            }
            const char* Ab = (const char*)As0 + buf * 8192;
            const char* Bb = (const char*)Bs0 + buf * 8192;
            int kread = (g4 * 16) ^ swz;
            short8 a[4], b[4];
            #pragma unroll
            for (int mi = 0; mi < 4; ++mi)
                a[mi] = *(const short8*)(Ab + (wr * 64 + mi * 16 + rl) * 64 + kread);
            #pragma unroll
            for (int ni = 0; ni < 4; ++ni)
                b[ni] = *(const short8*)(Bb + (wc * 64 + ni * 16 + rl) * 64 + kread);
            #pragma unroll
            for (int mi = 0; mi < 4; ++mi)
                #pragma unroll
                for (int ni = 0; ni < 4; ++ni)
                    acc[mi][ni] = __builtin_amdgcn_mfma_f32_16x16x32_bf16(
                        a[mi], b[ni], acc[mi][ni], 0, 0, 0);
            __syncthreads();
            buf ^= 1;
        }

        const float inv = 1.0f / (NSAMP - 1);
        #pragma unroll
        for (int mi = 0; mi < 4; ++mi)
            #pragma unroll
            for (int r = 0; r < 4; ++r) {
                int c = c0 + wr * 64 + mi * 16 + g4 * 4 + r;
                #pragma unroll
                for (int ni = 0; ni < 4; ++ni) {
                    int d = d0 + wc * 64 + ni * 16 + rl;
                    atomicAdd(&covf[((size_t)w * CN + c) * CN + d], acc[mi][ni][r] * inv);
                }
            }
    } else {
        // ======== qtrans role ========
        u16 (*S)[72] = (u16(*)[72])smem;            // [512][72]
        float* qm = (float*)(smem + 73728);         // [64]
        int qb = blockIdx.x - 300;
        int c0 = (qb & 7) * 64;
        int q  = qb >> 3;
        int lane = t & 63, cq = t >> 6;

        for (int cc = cq; cc < 64; cc += 4) {
            int c = c0 + cc;
            const float* p = x1 + ((size_t)q * CN + c) * HWN;
            float s = 0.f;
            for (int ic = 0; ic < 8; ++ic) {
                int i = ic * 64 + lane;
                float v = (i < HWN) ? p[i] : 0.f;
                s += v;
                S[i][cc] = f2b(v);
            }
            #pragma unroll
            for (int off = 32; off > 0; off >>= 1) s += __shfl_down(s, off);
            if (lane == 0) qm[cc] = s * (1.0f / HWN);
        }
        __syncthreads();

        int coct = t & 7;
        for (int p = 0; p < 16; ++p) {
            int il = p * 32 + (t >> 3);
            if (il >= HWN) continue;
            short8 v = *(const short8*)(&S[il][coct * 8]);
            short8 o;
            #pragma unroll
            for (int j = 0; j < 8; ++j) {
                float f = b2f((u16)v[j]) - qm[coct * 8 + j];
                o[j] = (short)f2b(f);
            }
            *(short8*)(Abf + ((size_t)(q * HWN + il)) * CN + c0 + coct * 8) = o;
        }
    }
}

// ---------------- covf -> covb bf16: lower-triangle(+diag) 128-blocks only; strict-lower x2 ----------------
__global__ void cov2b_kernel(const float* __restrict__ covf, u16* __restrict__ covb) {
    int i = blockIdx.x * 256 + threadIdx.x;        // w*CN*CN + c*CN + d
    int w = i >> 18;
    int cd = i & ((1 << 18) - 1);
    int c = cd >> 9, d = cd & 511;
    int cb = c >> 7, db = d >> 7;
    if (cb < db) return;                           // never read by gemm
    size_t src = ((size_t)w << 18) + ((size_t)c << 9) + d;
    float v = covf[src];
    if (cb > db) v *= 2.f;                         // fold symmetry weight into strict-lower blocks
    covb[i] = f2b(v);
}

// ---------------- main: 128x128 tile, 4 waves, 3 blocks/CU, paired triangular slices, ring-3 depth-2 ----------------
// Per (m,w): TWO balanced 20-chunk blocks (strict-lower covb blocks pre-scaled 2x):
//   ps=0: slice0 (d=[0,128),   K=[0,128),  4 ch) then slice3 (d=[384,512), K=[0,512), 16 ch)
//   ps=1: slice1 (d=[128,256), K=[0,256),  8 ch) then slice2 (d=[256,384), K=[0,384), 12 ch)
// Ring-3 LDS (slot = gc%3), depth-2 prefetch, steady-state vmcnt(4) — loads stay in flight
// across barriers (T4); covers L3/HBM straggler latency the depth-1 vmcnt(0) exposed.
__global__ __launch_bounds__(256, 3) void gemm128p_kernel(const u16* __restrict__ Abf,
                                                          const u16* __restrict__ covb,
                                                          float* __restrict__ simws) {
    __shared__ __align__(16) u16 As[3][128 * 32];
    __shared__ __align__(16) u16 Bs[3][128 * 32];
    __shared__ float simpart[128 * 3];

    int x = blockIdx.x & 7;
    int l = blockIdx.x >> 3;
    int g = l / 10;
    int m = x * 65 + g;
    if (m >= MT128) return;
    int inner = l - g * 10;
    int w  = inner % 5;
    int ps = inner / 5;                   // 0: {slice0, slice3}; 1: {slice1, slice2}
    int bnd   = (ps == 0) ? 4 : 8;        // chunk boundary between the two slices
    int dslA  = (ps == 0) ? 0 : 1;
    int dslB  = (ps == 0) ? 3 : 2;
    int r0 = m * 128;

    int t = threadIdx.x;
    int lane = t & 63, wid = t >> 6;
    int wr = wid >> 1, wc = wid & 1;        // 2M x 2N waves, wave tile 64x64
    int rl = lane & 15, g4 = lane >> 4;
    int swz = ((rl >> 1) & 3) << 4;
    int kread = (g4 * 16) ^ swz;

    const char* gA  = (const char*)(Abf + (size_t)r0 * CN);                      // row stride 1024 B
    const char* gBA = (const char*)(covb + ((size_t)w * CN + dslA * 128) * CN);  // slice-A B rows
    const char* gBB = (const char*)(covb + ((size_t)w * CN + dslB * 128) * CN);  // slice-B B rows

    f32x4 acc[4][4];
    float simreg[16];
    #pragma unroll
    for (int i = 0; i < 16; ++i) simreg[i] = 0.f;
    #pragma unroll
    for (int mi = 0; mi < 4; ++mi)
        #pragma unroll
        for (int ni = 0; ni < 4; ++ni)
            acc[mi][ni] = (f32x4){0.f, 0.f, 0.f, 0.f};

    // stage global chunk gc into ring slot gc%3: 2 A + 2 B gload16 per thread
    auto stage_chunk = [&](int gc) {
        bool second = (gc >= bnd);
        const char* gB = second ? gBB : gBA;
        int kbyte = (second ? (gc - bnd) : gc) * 64;
        int slot = gc % 3;
        #pragma unroll
        for (int j = 0; j < 2; ++j) {
            int off = j * 4096 + t * 16;
            int row = off >> 6;
            int kbs = (off & 63) ^ (((row >> 1) & 3) << 4);
            gload16(gA + (size_t)row * 1024 + kbyte + kbs, (char*)&As[slot][0] + off);
            gload16(gB + (size_t)row * 1024 + kbyte + kbs, (char*)&Bs[slot][0] + off);
        }
    };

    // merged chunk body (r14-proven): 8 ds_reads (b/a interleaved) then 16 MFMA
    auto do_chunk = [&](int gc) {
        int slot = gc % 3;
        const char* Ab = (const char*)&As[slot][0];
        const char* Bb = (const char*)&Bs[slot][0];
        short8 a[4], b[4];
        #pragma unroll
        for (int ni = 0; ni < 4; ++ni) {
            b[ni] = *(const short8*)(Bb + (wc * 64 + ni * 16 + rl) * 64 + kread);
            a[ni] = *(const short8*)(Ab + (wr * 64 + ni * 16 + rl) * 64 + kread);
        }
        __builtin_amdgcn_s_setprio(1);
        #pragma unroll
        for (int mi = 0; mi < 4; ++mi)
            #pragma unroll
            for (int ni = 0; ni < 4; ++ni)
                acc[mi][ni] = __builtin_amdgcn_mfma_f32_16x16x32_bf16(
                    a[mi], b[ni], acc[mi][ni], 0, 0, 0);
        __builtin_amdgcn_s_setprio(0);
    };

    // register-local sub-pass drain (r16-proven): rowdot acc with centered-q, reset acc
    auto drain = [&](int db) {
        #pragma unroll
        for (int mi = 0; mi < 4; ++mi) {
            #pragma unroll
            for (int r = 0; r < 4; ++r) {
                int Rl = wr * 64 + mi * 16 + g4 * 4 + r;
                size_t Rg = (size_t)r0 + Rl;
                float s = 0.f;
                #pragma unroll
                for (int ni = 0; ni < 4; ++ni) {
                    int d = db + wc * 64 + ni * 16 + rl;
                    s += acc[mi][ni][r] * b2f(Abf[Rg * CN + d]);
                }
                simreg[mi * 4 + r] += s;
            }
        }
        #pragma unroll
        for (int mi = 0; mi < 4; ++mi)
            #pragma unroll
            for (int ni = 0; ni < 4; ++ni)
                acc[mi][ni] = (f32x4){0.f, 0.f, 0.f, 0.f};
    };

    // prologue: 2 chunks in flight (depth-2)
    stage_chunk(0);
    stage_chunk(1);

    #pragma unroll 1
    for (int gc = 0; gc < 19; ++gc) {
        asm volatile("s_waitcnt vmcnt(4)" ::: "memory");   // chunk-gc loads landed; gc+1 stays in flight
        __builtin_amdgcn_s_barrier();
        asm volatile("" ::: "memory");
        if (gc + 2 < 20) stage_chunk(gc + 2);              // depth-2 prefetch into slot (gc+2)%3
        do_chunk(gc);
        if (gc == bnd - 1) drain(dslA * 128);              // slice-A done
    }
    asm volatile("s_waitcnt vmcnt(0)" ::: "memory");       // last chunk's loads
    __builtin_amdgcn_s_barrier();
    asm volatile("" ::: "memory");
    do_chunk(19);
    drain(dslB * 128);                                     // slice-B done

    // final reduce: simreg over 16-lane groups -> simpart -> atomicAdd
    #pragma unroll
    for (int idx = 0; idx < 16; ++idx) {
        float v = simreg[idx];
        v += __shfl_xor(v, 1);
        v += __shfl_xor(v, 2);
        v += __shfl_xor(v, 4);
        v += __shfl_xor(v, 8);
        int mi = idx >> 2, r = idx & 3;
        int Rl = wr * 64 + mi * 16 + g4 * 4 + r;
        if (rl == 0) simpart[Rl * 3 + wc] = v;
    }
    __syncthreads();
    if (t < 128) {
        float v = simpart[t * 3 + 0] + simpart[t * 3 + 1];
        atomicAdd(&simws[(size_t)w * MPAD2 + r0 + t], v);
    }
}

// ---------------- finish: act + conv dot + bias -> scores ----------------
__global__ void finish_kernel(const float* __restrict__ simws,
                              const float* __restrict__ conv_w,
                              const float* __restrict__ conv_b,
                              float* __restrict__ scores) {
    int q = blockIdx.x, w = blockIdx.y;
    int t = threadIdx.x;    // 128
    const float* sp = simws + (size_t)w * MPAD2 + q * HWN;
    float s = 0.f;
    for (int i = t; i < HWN; i += 128) {
        float v = sp[i];
        float a = (v >= 0.f) ? v : 0.2f * v;
        s += a * conv_w[i];
    }
    __shared__ float red[2];
    #pragma unroll
    for (int off = 32; off > 0; off >>= 1) s += __shfl_down(s, off);
    if ((t & 63) == 0) red[t >> 6] = s;
    __syncthreads();
    if (t == 0) scores[q * WAYN + w] = red[0] + red[1] + conv_b[0];
}

extern "C" void kernel_launch(void* const* d_in, const int* in_sizes, int n_in,
                              void* d_out, int out_size, void* d_ws, size_t ws_size,
                              hipStream_t stream) {
    const float* x1     = (const float*)d_in[0];
    const float* x2     = (const float*)d_in[1];
    const float* conv_w = (const float*)d_in[2];
    const float* conv_b = (const float*)d_in[3];
    float* scores = (float*)d_out;

    char* ws = (char*)d_ws;
    u16* covb    = (u16*)ws;                               // 2,621,440 B
    float* simws = (float*)(ws + 2631680);                 // 1,326,080 B
    float* covf  = (float*)(ws + 3957760);                 // 5,242,880 B
    u16* x2c     = (u16*)(ws + 9200640);                   // 11,304,960 B (own region: prep2 overlap)
    u16* Abf     = (u16*)(ws + 20505600);                  // 66304*512*2 = 67,895,296 B

    prep1_kernel<<<896, 256, 0, stream>>>(x2, x2c, simws, covf, (u32*)(Abf + (size_t)MROWS * CN));
    prep2_kernel<<<1500, 256, 0, stream>>>(x2c, covf, x1, Abf);
    cov2b_kernel<<<WAYN * CN * CN / 256, 256, 0, stream>>>(covf, covb);
    gemm128p_kernel<<<8 * 65 * 10, 256, 0, stream>>>(Abf, covb, simws);
    finish_kernel<<<dim3(QN, WAYN), 128, 0, stream>>>(simws, conv_w, conv_b, scores);
}